// Round 4
// baseline (99.280 us; speedup 1.0000x reference)
//
#include <hip/hip_runtime.h>
#include <math.h>

#define NITV 17
#define NCELL (NITV*NITV)        // 289
#define CELLF 6
#define AGG_N (NCELL*CELLF)      // 1734
#define QSCALE 4194304.0f        // 2^22 fixed-point scale for deterministic i64 stats
#define QINV   (1.0/4194304.0)

// ws layout: bytes [0, AGG_N*8) = global u64 aggregate (zeroed via hipMemsetAsync each call).

// ---------------- Kernel 1: deterministic joint histogram ----------------
// Per sample: cell (iv0,iv2) from 16+16 threshold compares; 6 stats quantized
// to i64 -> LDS u64 atomics (2 replicas) -> one global u64 atomicAdd per
// nonzero counter per block. Integer adds are exactly associative => fully
// deterministic regardless of scheduling.
__global__ void __launch_bounds__(256) hist_kernel(
    const float* __restrict__ x,
    const float* __restrict__ ehr_w, const float* __restrict__ ehr_b,
    const float* __restrict__ bio_w, const float* __restrict__ bio_b,
    unsigned long long* __restrict__ agg, int B)
{
  __shared__ unsigned long long acc[2][AGG_N];   // 27.7 KB
  __shared__ float thr[32];
  const int tid = threadIdx.x;
  if (tid < 16) {
    float w = ehr_w[tid], b = ehr_b[tid];
    thr[tid] = (w == 0.0f) ? __builtin_inff() : (-b / w);
  } else if (tid < 32) {
    int k = tid - 16;
    float w = bio_w[k], b = bio_b[k];
    thr[16+k] = (w == 0.0f) ? __builtin_inff() : (-b / w);
  }
  {
    unsigned long long* af = &acc[0][0];
    for (int i = tid; i < 2*AGG_N; i += 256) af[i] = 0ull;
  }
  __syncthreads();
  float tE[16], tB[16];
  #pragma unroll
  for (int k = 0; k < 16; ++k) { tE[k] = thr[k]; tB[k] = thr[16+k]; }
  const int rep = tid & 1;
  const int s0 = (blockIdx.x*256 + tid)*4;

  float xs0[4], xs2[4];
  int nv = 0;
  if (s0 + 4 <= B) {
    const float4* xp = (const float4*)(x + (size_t)s0*3);
    float4 a = xp[0], b = xp[1], c = xp[2];
    xs0[0]=a.x; xs2[0]=a.z;  xs0[1]=a.w; xs2[1]=b.y;
    xs0[2]=b.z; xs2[2]=c.x;  xs0[3]=c.y; xs2[3]=c.w;
    nv = 4;
  } else {
    for (int u = 0; u < 4; ++u) {
      int i = s0 + u;
      if (i < B) { xs0[nv] = x[3*(size_t)i]; xs2[nv] = x[3*(size_t)i+2]; ++nv; }
    }
  }
  for (int u = 0; u < nv; ++u) {
    float x0 = xs0[u], x2 = xs2[u];
    int iv0 = 0, iv2 = 0;
    #pragma unroll
    for (int k = 0; k < 16; ++k) { iv0 += (tE[k] < x0); iv2 += (tB[k] < x2); }
    unsigned long long* c = &acc[rep][(iv0*NITV + iv2)*CELLF];
    long long q1 = llrintf(x0*QSCALE);
    long long q2 = llrintf(x2*QSCALE);
    long long q3 = llrintf(x0*x0*QSCALE);
    long long q4 = llrintf(x2*x2*QSCALE);
    long long q5 = llrintf(x0*x2*QSCALE);
    atomicAdd(c+0, 1ull);
    atomicAdd(c+1, (unsigned long long)q1);
    atomicAdd(c+2, (unsigned long long)q2);
    atomicAdd(c+3, (unsigned long long)q3);
    atomicAdd(c+4, (unsigned long long)q4);
    atomicAdd(c+5, (unsigned long long)q5);
  }
  __syncthreads();
  for (int i = tid; i < AGG_N; i += 256) {
    unsigned long long s = acc[0][i] + acc[1][i];
    if (s) atomicAdd(&agg[i], s);
  }
}

// ---------------- Kernel 2: fused setup + finalize + apply ----------------
// Every block redundantly rebuilds the interval tables (float; identical
// results per block), reads the global u64 aggregate, computes BN scale/shift
// (double), scales tables into padded LDS, then applies to its 4 samples/thread.
__global__ void __launch_bounds__(256, 4) fused_kernel(
    const float* __restrict__ x,
    const float* __restrict__ ehr_w, const float* __restrict__ ehr_b,
    const float* __restrict__ bio_w, const float* __restrict__ bio_b,
    const float* __restrict__ bio_qkv_w, const float* __restrict__ bio_qkv_b,
    const float* __restrict__ ehr_qkv_w, const float* __restrict__ ehr_qkv_b,
    const float* __restrict__ attn_in_w, const float* __restrict__ attn_in_b,
    const float* __restrict__ attn_out_w, const float* __restrict__ attn_out_b,
    const float* __restrict__ ab_proj_w, const float* __restrict__ ab_proj_b,
    const float* __restrict__ f1_w, const float* __restrict__ f1_b,
    const unsigned long long* __restrict__ agg,
    const float* __restrict__ bn_g, const float* __restrict__ bn_b,
    const float* __restrict__ f2_w, const float* __restrict__ f2_b,
    float* __restrict__ out, int B)
{
  // R: raw tables [tbl][itv][j], tbl = {Ue,Ve,Ub,Vb}, 4*17*64 floats.
  __shared__ float R[4352];                       // 17.4 KB, persists setup -> tab build
  // S: overlaid scratch: setup GEMMs (4352 fl) / aggd+shp (4492 fl) / tab (4624 fl)
  __shared__ __align__(16) float S[4624];         // 18.5 KB
  __shared__ float wEx[16], bEx[16], cEx[16], tEx[16];
  __shared__ float wBx[16], bBx[16], cBx[16], tBx[16];
  __shared__ int   rkE[16], rkB[16];
  __shared__ float mvec[16], uvec[16], vvec[16], cab[16], h0p[64];
  __shared__ float st[128];                       // s[64], t[64]
  const int tid = threadIdx.x;

  // Issue x loads early; consumed only in phase C.
  const int s0 = (blockIdx.x*256 + tid)*4;
  float xs0[4], xs2[4];
  int nv = 0;
  if (s0 + 4 <= B) {
    const float4* xp = (const float4*)(x + (size_t)s0*3);
    float4 a = xp[0], b = xp[1], c = xp[2];
    xs0[0]=a.x; xs2[0]=a.z;  xs0[1]=a.w; xs2[1]=b.y;
    xs0[2]=b.z; xs2[2]=c.x;  xs0[3]=c.y; xs2[3]=c.w;
    nv = 4;
  } else {
    for (int u = 0; u < 4; ++u) {
      int i = s0 + u;
      if (i < B) { xs0[nv] = x[3*(size_t)i]; xs2[nv] = x[3*(size_t)i+2]; ++nv; }
    }
  }

  float* M  = S;          // 256
  float* P1 = S + 256;
  float* P2 = S + 512;
  float* Ae = S + 768;
  float* Ab = S + 1024;
  float* G  = S + 1280;   // 1024
  float* Ge = S + 2304;   // 1024
  float* Gb = S + 3328;   // 1024 (ends 4352)

  // Region 1: M = Wo @ Wv ; m = Wo @ bv + bo   (all float: 16-term dots, err ~1e-6)
  {
    int o = tid >> 4, k = tid & 15;
    float s = 0.f;
    for (int j = 0; j < 16; ++j)
      s = fmaf(attn_out_w[o*16+j], attn_in_w[(32+j)*16+k], s);
    M[tid] = s;
  }
  if (tid < 16) {
    float s = attn_out_b[tid];
    for (int j = 0; j < 16; ++j)
      s = fmaf(attn_out_w[tid*16+j], attn_in_b[32+j], s);
    mvec[tid] = s;
  }
  __syncthreads();

  // Region 2: P1,P2 = ab_proj halves @ M ; uvec,vvec ; G = F1a + F1b@M
  {
    int o = tid >> 4, i = tid & 15;
    float s1 = 0.f, s2 = 0.f;
    for (int t = 0; t < 16; ++t) {
      float mt = M[t*16+i];
      s1 = fmaf(ab_proj_w[o*32+t],    mt, s1);
      s2 = fmaf(ab_proj_w[o*32+16+t], mt, s2);
    }
    P1[tid] = s1; P2[tid] = s2;
  }
  if (tid < 16) {
    float su = mvec[tid], sv = mvec[tid];
    for (int i = 0; i < 16; ++i) {
      float mt = M[tid*16+i];
      su = fmaf(mt, ehr_qkv_b[32+i], su);
      sv = fmaf(mt, bio_qkv_b[32+i], sv);
    }
    uvec[tid] = su; vvec[tid] = sv;
  }
  for (int idx = tid; idx < 1024; idx += 256) {
    int j = idx >> 4, k = idx & 15;
    float s = f1_w[j*32+k];
    for (int i = 0; i < 16; ++i)
      s = fmaf(f1_w[j*32+16+i], M[i*16+k], s);
    G[idx] = s;
  }
  __syncthreads();

  // Region 3: Ae = P1@Wev, Ab = P2@Wbv ; cab ; per-unit thresholds
  {
    int o = tid >> 4, k = tid & 15;
    float s1 = 0.f, s2 = 0.f;
    for (int i = 0; i < 16; ++i) {
      s1 = fmaf(P1[o*16+i], ehr_qkv_w[(32+i)*16+k], s1);
      s2 = fmaf(P2[o*16+i], bio_qkv_w[(32+i)*16+k], s2);
    }
    Ae[tid] = s1; Ab[tid] = s2;
  }
  if (tid < 16) {
    float s = ab_proj_b[tid];
    for (int t = 0; t < 16; ++t) {
      s = fmaf(ab_proj_w[tid*32+t],    uvec[t], s);
      s = fmaf(ab_proj_w[tid*32+16+t], vvec[t], s);
    }
    cab[tid] = s;
  }
  if (tid < 16) {
    float w = ehr_w[tid], b = ehr_b[tid];
    bool z = (w == 0.0f);
    wEx[tid] = z ? 0.f : w;
    bEx[tid] = z ? 0.f : b;
    cEx[tid] = z ? fmaxf(b, 0.f) : 0.f;
    tEx[tid] = z ? __builtin_inff() : (-b / w);
  } else if (tid < 32) {
    int k = tid - 16;
    float w = bio_w[k], b = bio_b[k];
    bool z = (w == 0.0f);
    wBx[k] = z ? 0.f : w;
    bBx[k] = z ? 0.f : b;
    cBx[k] = z ? fmaxf(b, 0.f) : 0.f;
    tBx[k] = z ? __builtin_inff() : (-b / w);
  }
  __syncthreads();

  // Region 4: Ge = G@Ae, Gb = G@Ab ; h0 ; threshold ranks
  for (int idx = tid; idx < 1024; idx += 256) {
    int j = idx >> 4, k = idx & 15;
    float s1 = 0.f, s2 = 0.f;
    for (int i = 0; i < 16; ++i) {
      float g = G[j*16+i];
      s1 = fmaf(g, Ae[i*16+k], s1);
      s2 = fmaf(g, Ab[i*16+k], s2);
    }
    Ge[idx] = s1; Gb[idx] = s2;
  }
  if (tid < 64) {
    float s = f1_b[tid];
    for (int i = 0; i < 16; ++i) {
      s = fmaf(G[tid*16+i], cab[i], s);
      s = fmaf(f1_w[tid*32+16+i], mvec[i], s);
    }
    h0p[tid] = s;
  }
  if (tid < 16) {
    int r = 0;
    for (int j = 0; j < 16; ++j)
      r += (tEx[j] < tEx[tid]) || (tEx[j] == tEx[tid] && j < tid);
    rkE[tid] = r;
  } else if (tid < 32) {
    int k = tid - 16, r = 0;
    for (int j = 0; j < 16; ++j)
      r += (tBx[j] < tBx[k]) || (tBx[j] == tBx[k] && j < k);
    rkB[k] = r;
  }
  __syncthreads();

  // Region 5: fold zero-slope (constant) units into h0
  if (tid < 64) {
    float s = h0p[tid];
    for (int k = 0; k < 16; ++k)
      s += Ge[tid*16+k]*cEx[k] + Gb[tid*16+k]*cBx[k];
    h0p[tid] = s;
  }
  __syncthreads();

  // Region 6: raw interval tables into R  (R[tbl*1088 + itv*64 + j])
  for (int idx = tid; idx < NITV*64; idx += 256) {
    int i = idx >> 6, j = idx & 63;
    float ue = 0.f, ve = 0.f, ub = 0.f, vb = 0.f;
    for (int k = 0; k < 16; ++k) {
      bool actE = (wEx[k] > 0.f) ? (rkE[k] < i) : (rkE[k] >= i);
      bool actB = (wBx[k] > 0.f) ? (rkB[k] < i) : (rkB[k] >= i);
      if (actE) { ue = fmaf(Ge[j*16+k], wEx[k], ue); ve = fmaf(Ge[j*16+k], bEx[k], ve); }
      if (actB) { ub = fmaf(Gb[j*16+k], wBx[k], ub); vb = fmaf(Gb[j*16+k], bBx[k], vb); }
    }
    R[idx]        = ue;
    R[1088 + idx] = ve + h0p[j];   // constants folded into Ve
    R[2176 + idx] = ub;
    R[3264 + idx] = vb;
  }
  __syncthreads();

  // ---- Finalize (redundant per block, double precision) ----
  double* aggd = (double*)S;            // 1734 doubles (S[0..3468))
  double* shp  = (double*)(S + 3468);   // 4*64 doubles
  double* sh2p = (double*)(S + 3980);   // 4*64 doubles (ends 4492)
  for (int i = tid; i < AGG_N; i += 256) {
    long long v = (long long)agg[i];
    aggd[i] = (i % 6 == 0) ? (double)v : (double)v * QINV;
  }
  __syncthreads();
  {
    const int j = tid & 63, pg = tid >> 6;
    double sh = 0, sh2 = 0;
    for (int p = pg; p < NITV; p += 4) {
      const double Ue = (double)R[p*64+j];
      const double Ve = (double)R[1088 + p*64+j];
      for (int q = 0; q < NITV; ++q) {
        const double* c = &aggd[(p*NITV+q)*CELLF];
        double n = c[0], sx0 = c[1], sx2 = c[2], s00 = c[3], s22 = c[4], s02 = c[5];
        double Ub = (double)R[2176 + q*64+j];
        double Vb = (double)R[3264 + q*64+j];
        sh  += sx0*Ue + n*Ve + sx2*Ub + n*Vb;
        sh2 += s00*Ue*Ue + 2.0*sx0*Ue*Ve + n*Ve*Ve
             + s22*Ub*Ub + 2.0*sx2*Ub*Vb + n*Vb*Vb
             + 2.0*(s02*Ue*Ub + sx0*Ue*Vb + sx2*Ve*Ub + n*Ve*Vb);
      }
    }
    shp[pg*64+j] = sh; sh2p[pg*64+j] = sh2;
  }
  __syncthreads();
  if (tid < 64) {
    const int j = tid;
    double sh  = (shp[j]      + shp[64+j])  + (shp[128+j]  + shp[192+j]);
    double sh2 = (sh2p[j]     + sh2p[64+j]) + (sh2p[128+j] + sh2p[192+j]);
    const double invB = 1.0 / (double)B;
    double mu  = sh * invB;
    double var = sh2 * invB - mu*mu;
    double s   = (double)bn_g[j] / sqrt(var + 1e-5);
    double t   = (double)bn_b[j] - mu*s;
    st[j]    = (float)s;
    st[64+j] = (float)t;
  }
  __syncthreads();

  // ---- Build scaled padded tables in S (tab[tbl*1156 + itv*68 + j]) ----
  for (int idx = tid; idx < 4352; idx += 256) {
    int tbl = idx / 1088, rem = idx - tbl*1088;
    int itv = rem >> 6, j = rem & 63;
    float o = st[j] * R[idx];
    if (tbl == 1) o += st[64+j];
    S[tbl*1156 + itv*68 + j] = o;
  }
  __syncthreads();

  // ---- Phase C: apply ----
  const float* LUe = S;
  const float* LVe = S + 1156;
  const float* LUb = S + 2312;
  const float* LVb = S + 3468;
  float tE[16], tB[16];
  #pragma unroll
  for (int k = 0; k < 16; ++k) { tE[k] = tEx[k]; tB[k] = tBx[k]; }
  const float b0 = f2_b[0], b1 = f2_b[1], b2 = f2_b[2];

  float res[12];
  #pragma unroll
  for (int u = 0; u < 4; ++u) {
    if (u >= nv) break;
    float x0 = xs0[u], x2 = xs2[u];
    int iv0 = 0, iv2 = 0;
    #pragma unroll
    for (int k = 0; k < 16; ++k) { iv0 += (tE[k] < x0); iv2 += (tB[k] < x2); }
    const float4* ue4 = (const float4*)&LUe[iv0*68];
    const float4* ve4 = (const float4*)&LVe[iv0*68];
    const float4* ub4 = (const float4*)&LUb[iv2*68];
    const float4* vb4 = (const float4*)&LVb[iv2*68];
    float a0 = b0, a1 = b1, a2 = b2;
    #pragma unroll
    for (int g = 0; g < 16; ++g) {
      float4 ue = ue4[g], ve = ve4[g], ub = ub4[g], vb = vb4[g];
      const int j = g*4;
      float h, r;
      h = fmaf(x0, ue.x, ve.x) + fmaf(x2, ub.x, vb.x); r = fmaxf(h, 0.f);
      a0 = fmaf(r, f2_w[j+0],     a0); a1 = fmaf(r, f2_w[64+j+0],  a1); a2 = fmaf(r, f2_w[128+j+0], a2);
      h = fmaf(x0, ue.y, ve.y) + fmaf(x2, ub.y, vb.y); r = fmaxf(h, 0.f);
      a0 = fmaf(r, f2_w[j+1],     a0); a1 = fmaf(r, f2_w[64+j+1],  a1); a2 = fmaf(r, f2_w[128+j+1], a2);
      h = fmaf(x0, ue.z, ve.z) + fmaf(x2, ub.z, vb.z); r = fmaxf(h, 0.f);
      a0 = fmaf(r, f2_w[j+2],     a0); a1 = fmaf(r, f2_w[64+j+2],  a1); a2 = fmaf(r, f2_w[128+j+2], a2);
      h = fmaf(x0, ue.w, ve.w) + fmaf(x2, ub.w, vb.w); r = fmaxf(h, 0.f);
      a0 = fmaf(r, f2_w[j+3],     a0); a1 = fmaf(r, f2_w[64+j+3],  a1); a2 = fmaf(r, f2_w[128+j+3], a2);
    }
    res[u*3+0] = a0; res[u*3+1] = a1; res[u*3+2] = a2;
  }
  if (nv == 4) {
    float4* op = (float4*)(out + (size_t)s0*3);
    op[0] = make_float4(res[0], res[1], res[2],  res[3]);
    op[1] = make_float4(res[4], res[5], res[6],  res[7]);
    op[2] = make_float4(res[8], res[9], res[10], res[11]);
  } else {
    for (int u = 0; u < nv; ++u) {
      size_t i = (size_t)(s0 + u);
      out[3*i+0] = res[u*3+0]; out[3*i+1] = res[u*3+1]; out[3*i+2] = res[u*3+2];
    }
  }
}

extern "C" void kernel_launch(void* const* d_in, const int* in_sizes, int n_in,
                              void* d_out, int out_size, void* d_ws, size_t ws_size,
                              hipStream_t stream) {
  const float* x          = (const float*)d_in[0];
  const float* ehr_w      = (const float*)d_in[1];
  const float* ehr_b      = (const float*)d_in[2];
  const float* bio_w      = (const float*)d_in[5];
  const float* bio_b      = (const float*)d_in[6];
  const float* bio_qkv_w  = (const float*)d_in[7];
  const float* bio_qkv_b  = (const float*)d_in[8];
  const float* ehr_qkv_w  = (const float*)d_in[9];
  const float* ehr_qkv_b  = (const float*)d_in[10];
  const float* attn_in_w  = (const float*)d_in[13];
  const float* attn_in_b  = (const float*)d_in[14];
  const float* attn_out_w = (const float*)d_in[15];
  const float* attn_out_b = (const float*)d_in[16];
  const float* ab_proj_w  = (const float*)d_in[17];
  const float* ab_proj_b  = (const float*)d_in[18];
  const float* f1_w       = (const float*)d_in[19];
  const float* f1_b       = (const float*)d_in[20];
  const float* bn_g       = (const float*)d_in[21];
  const float* bn_b       = (const float*)d_in[22];
  const float* f2_w       = (const float*)d_in[23];
  const float* f2_b       = (const float*)d_in[24];
  float* out = (float*)d_out;
  unsigned long long* agg = (unsigned long long*)d_ws;
  const int B = in_sizes[0] / 3;
  const int nblk = (B + 1023) / 1024;   // 4 samples/thread, 256 threads

  hipMemsetAsync(d_ws, 0, AGG_N*sizeof(unsigned long long), stream);
  hist_kernel<<<nblk, 256, 0, stream>>>(x, ehr_w, ehr_b, bio_w, bio_b, agg, B);
  fused_kernel<<<nblk, 256, 0, stream>>>(x, ehr_w, ehr_b, bio_w, bio_b,
      bio_qkv_w, bio_qkv_b, ehr_qkv_w, ehr_qkv_b,
      attn_in_w, attn_in_b, attn_out_w, attn_out_b,
      ab_proj_w, ab_proj_b, f1_w, f1_b,
      agg, bn_g, bn_b, f2_w, f2_b, out, B);
}

// Round 7
// 88.484 us; speedup vs baseline: 1.1220x; 1.1220x over previous
//
#include <hip/hip_runtime.h>
#include <math.h>

#define NITV 17
#define NCELL (NITV*NITV)        // 289
#define CELLF 6
#define AGG_N (NCELL*CELLF)      // 1734
#define NREP 4                   // hist LDS replicas (i32)
#define QS   4096.0f             // 2^12 fixed-point scale (deterministic i64 stats)
#define QINV (1.0/4096.0)

// ws dword-offset layout:
//   [0 .. 3468)   u64 agg[1734] (memset to 0 each launch)
#define RAW_OFF  3468  // raw tables f32: Ue[17*64], +1088 Ve, +2176 Ub, +3264 Vb
#define THR_OFF  7820  // sorted thresholds tE[16], tB[16]
#define EVT_OFF  7856  // scaled E-table transposed [32 pair][17 itv] float4 (2176 dw)
#define BVT_OFF  10032 // scaled B-table transposed (2176 dw) -> ends 12208

// count of sorted t[0..15] strictly less than x.
// 4-level branchless binary search gives min(count,15); the t[15] fix-up
// covers count==16 (sorted => t[15]<x implies all 16 below x).
__device__ __forceinline__ int bsearch17(const float* t, float x) {
  bool c8 = t[7] < x;
  float s2 = c8 ? t[11] : t[3];
  bool c4 = s2 < x;
  float sa = c8 ? t[13] : t[5];
  float sb = c8 ? t[9]  : t[1];
  float s3 = c4 ? sa : sb;
  bool c2 = s3 < x;
  float v00 = c2 ? t[2]  : t[0];
  float v01 = c2 ? t[6]  : t[4];
  float v10 = c2 ? t[10] : t[8];
  float v11 = c2 ? t[14] : t[12];
  float w0 = c4 ? v01 : v00;
  float w1 = c4 ? v11 : v10;
  float s4 = c8 ? w1 : w0;
  bool c1 = s4 < x;
  int c = (c8?8:0) + (c4?4:0) + (c2?2:0) + (c1?1:0);
  c += (t[15] < x) ? 1 : 0;
  return c;
}

// ------------- Kernel 1: deterministic joint histogram (+ setup in last block) -------------
__global__ void __launch_bounds__(256) hist_kernel(
    const float* __restrict__ x,
    const float* __restrict__ ehr_w, const float* __restrict__ ehr_b,
    const float* __restrict__ bio_w, const float* __restrict__ bio_b,
    const float* __restrict__ bio_qkv_w, const float* __restrict__ bio_qkv_b,
    const float* __restrict__ ehr_qkv_w, const float* __restrict__ ehr_qkv_b,
    const float* __restrict__ attn_in_w, const float* __restrict__ attn_in_b,
    const float* __restrict__ attn_out_w, const float* __restrict__ attn_out_b,
    const float* __restrict__ ab_proj_w, const float* __restrict__ ab_proj_b,
    const float* __restrict__ f1_w, const float* __restrict__ f1_b,
    unsigned long long* __restrict__ agg, float* __restrict__ ws,
    int B, int nblk)
{
  __shared__ int accS[NREP*AGG_N];   // 27.7 KB; setup block reuses as float scratch
  __shared__ float thrS[32];
  __shared__ float mvec[16], uvec[16], vvec[16], cab[16], h0p[64];
  __shared__ float wEx[16], bEx[16], cEx[16], tEx[16];
  __shared__ float wBx[16], bBx[16], cBx[16], tBx[16];
  __shared__ int   rkE[16], rkB[16];
  const int tid = threadIdx.x;

  if ((int)blockIdx.x == nblk) {
    // ---------------- setup-only block: build raw tables once ----------------
    float* S  = (float*)accS;       // 4352 floats needed <= 6936 available
    float* M  = S;
    float* P1 = S + 256;
    float* P2 = S + 512;
    float* Ae = S + 768;
    float* Ab = S + 1024;
    float* G  = S + 1280;
    float* Ge = S + 2304;
    float* Gb = S + 3328;

    // Region 1: M = Wo @ Wv (attn V-slice); m = Wo @ bv + bo
    {
      int o = tid >> 4, k = tid & 15;
      float s = 0.f;
      for (int j = 0; j < 16; ++j)
        s = fmaf(attn_out_w[o*16+j], attn_in_w[(32+j)*16+k], s);
      M[tid] = s;
    }
    if (tid < 16) {
      float s = attn_out_b[tid];
      for (int j = 0; j < 16; ++j)
        s = fmaf(attn_out_w[tid*16+j], attn_in_b[32+j], s);
      mvec[tid] = s;
    }
    __syncthreads();

    // Region 2: P1,P2 = ab_proj halves @ M ; uvec,vvec ; G = F1a + F1b@M
    {
      int o = tid >> 4, i = tid & 15;
      float s1 = 0.f, s2 = 0.f;
      for (int t = 0; t < 16; ++t) {
        float mt = M[t*16+i];
        s1 = fmaf(ab_proj_w[o*32+t],    mt, s1);
        s2 = fmaf(ab_proj_w[o*32+16+t], mt, s2);
      }
      P1[tid] = s1; P2[tid] = s2;
    }
    if (tid < 16) {
      float su = mvec[tid], sv = mvec[tid];
      for (int i = 0; i < 16; ++i) {
        float mt = M[tid*16+i];
        su = fmaf(mt, ehr_qkv_b[32+i], su);
        sv = fmaf(mt, bio_qkv_b[32+i], sv);
      }
      uvec[tid] = su; vvec[tid] = sv;
    }
    for (int idx = tid; idx < 1024; idx += 256) {
      int j = idx >> 4, k = idx & 15;
      float s = f1_w[j*32+k];
      for (int i = 0; i < 16; ++i)
        s = fmaf(f1_w[j*32+16+i], M[i*16+k], s);
      G[idx] = s;
    }
    __syncthreads();

    // Region 3: Ae = P1@Wev, Ab = P2@Wbv ; cab ; per-unit thresholds
    {
      int o = tid >> 4, k = tid & 15;
      float s1 = 0.f, s2 = 0.f;
      for (int i = 0; i < 16; ++i) {
        s1 = fmaf(P1[o*16+i], ehr_qkv_w[(32+i)*16+k], s1);
        s2 = fmaf(P2[o*16+i], bio_qkv_w[(32+i)*16+k], s2);
      }
      Ae[tid] = s1; Ab[tid] = s2;
    }
    if (tid < 16) {
      float s = ab_proj_b[tid];
      for (int t = 0; t < 16; ++t) {
        s = fmaf(ab_proj_w[tid*32+t],    uvec[t], s);
        s = fmaf(ab_proj_w[tid*32+16+t], vvec[t], s);
      }
      cab[tid] = s;
    }
    if (tid < 16) {
      float w = ehr_w[tid], b = ehr_b[tid];
      bool z = (w == 0.0f);
      wEx[tid] = z ? 0.f : w;
      bEx[tid] = z ? 0.f : b;
      cEx[tid] = z ? fmaxf(b, 0.f) : 0.f;
      tEx[tid] = z ? __builtin_inff() : (-b / w);
    } else if (tid < 32) {
      int k = tid - 16;
      float w = bio_w[k], b = bio_b[k];
      bool z = (w == 0.0f);
      wBx[k] = z ? 0.f : w;
      bBx[k] = z ? 0.f : b;
      cBx[k] = z ? fmaxf(b, 0.f) : 0.f;
      tBx[k] = z ? __builtin_inff() : (-b / w);
    }
    __syncthreads();

    // Region 4: Ge = G@Ae, Gb = G@Ab ; h0 ; threshold ranks
    for (int idx = tid; idx < 1024; idx += 256) {
      int j = idx >> 4, k = idx & 15;
      float s1 = 0.f, s2 = 0.f;
      for (int i = 0; i < 16; ++i) {
        float g = G[j*16+i];
        s1 = fmaf(g, Ae[i*16+k], s1);
        s2 = fmaf(g, Ab[i*16+k], s2);
      }
      Ge[idx] = s1; Gb[idx] = s2;
    }
    if (tid < 64) {
      float s = f1_b[tid];
      for (int i = 0; i < 16; ++i) {
        s = fmaf(G[tid*16+i], cab[i], s);
        s = fmaf(f1_w[tid*32+16+i], mvec[i], s);
      }
      h0p[tid] = s;
    }
    if (tid < 16) {
      int r = 0;
      for (int j = 0; j < 16; ++j)
        r += (tEx[j] < tEx[tid]) || (tEx[j] == tEx[tid] && j < tid);
      rkE[tid] = r;
    } else if (tid < 32) {
      int k = tid - 16, r = 0;
      for (int j = 0; j < 16; ++j)
        r += (tBx[j] < tBx[k]) || (tBx[j] == tBx[k] && j < k);
      rkB[k] = r;
    }
    __syncthreads();

    // Region 5: fold zero-slope units into h0
    if (tid < 64) {
      float s = h0p[tid];
      for (int k = 0; k < 16; ++k)
        s += Ge[tid*16+k]*cEx[k] + Gb[tid*16+k]*cBx[k];
      h0p[tid] = s;
    }
    __syncthreads();

    // Region 6: raw interval tables -> ws (f32); sorted thresholds -> ws
    for (int idx = tid; idx < NITV*64; idx += 256) {
      int i = idx >> 6, j = idx & 63;
      float ue = 0.f, ve = 0.f, ub = 0.f, vb = 0.f;
      for (int k = 0; k < 16; ++k) {
        bool actE = (wEx[k] > 0.f) ? (rkE[k] < i) : (rkE[k] >= i);
        bool actB = (wBx[k] > 0.f) ? (rkB[k] < i) : (rkB[k] >= i);
        if (actE) { ue = fmaf(Ge[j*16+k], wEx[k], ue); ve = fmaf(Ge[j*16+k], bEx[k], ve); }
        if (actB) { ub = fmaf(Gb[j*16+k], wBx[k], ub); vb = fmaf(Gb[j*16+k], bBx[k], vb); }
      }
      ws[RAW_OFF + idx]        = ue;
      ws[RAW_OFF + 1088 + idx] = ve + h0p[j];   // constants folded into Ve
      ws[RAW_OFF + 2176 + idx] = ub;
      ws[RAW_OFF + 3264 + idx] = vb;
    }
    if (tid < 16) {
      ws[THR_OFF + rkE[tid]]      = tEx[tid];
      ws[THR_OFF + 16 + rkB[tid]] = tBx[tid];
    }
    return;
  }

  // ---------------- histogram path ----------------
  if (tid < 16) {
    float tloc[16];
    #pragma unroll
    for (int j = 0; j < 16; ++j) {
      float w = ehr_w[j], b = ehr_b[j];
      tloc[j] = (w == 0.0f) ? __builtin_inff() : (-b / w);
    }
    float mine = tloc[tid];
    int r = 0;
    #pragma unroll
    for (int j = 0; j < 16; ++j)
      r += (tloc[j] < mine) || (tloc[j] == mine && j < tid);
    thrS[r] = mine;
  } else if (tid < 32) {
    int k = tid - 16;
    float tloc[16];
    #pragma unroll
    for (int j = 0; j < 16; ++j) {
      float w = bio_w[j], b = bio_b[j];
      tloc[j] = (w == 0.0f) ? __builtin_inff() : (-b / w);
    }
    float mine = tloc[k];
    int r = 0;
    #pragma unroll
    for (int j = 0; j < 16; ++j)
      r += (tloc[j] < mine) || (tloc[j] == mine && j < k);
    thrS[16 + r] = mine;
  }
  for (int i = tid; i < NREP*AGG_N; i += 256) accS[i] = 0;
  __syncthreads();

  float te[16], tb[16];
  #pragma unroll
  for (int k = 0; k < 16; ++k) { te[k] = thrS[k]; tb[k] = thrS[16+k]; }
  const int rep = tid & (NREP-1);
  const int s0 = (blockIdx.x*256 + tid)*4;

  float xs0[4], xs2[4];
  int nv = 0;
  if (s0 + 4 <= B) {
    const float4* xp = (const float4*)(x + (size_t)s0*3);
    float4 a = xp[0], b = xp[1], c = xp[2];
    xs0[0]=a.x; xs2[0]=a.z;  xs0[1]=a.w; xs2[1]=b.y;
    xs0[2]=b.z; xs2[2]=c.x;  xs0[3]=c.y; xs2[3]=c.w;
    nv = 4;
  } else {
    for (int u = 0; u < 4; ++u) {
      int i = s0 + u;
      if (i < B) { xs0[nv] = x[3*(size_t)i]; xs2[nv] = x[3*(size_t)i+2]; ++nv; }
    }
  }
  for (int u = 0; u < nv; ++u) {
    float x0 = xs0[u], x2 = xs2[u];
    int iv0 = bsearch17(te, x0);
    int iv2 = bsearch17(tb, x2);
    int* c = &accS[rep*AGG_N + (iv0*NITV + iv2)*CELLF];
    atomicAdd(c+0, 1);
    atomicAdd(c+1, __float2int_rn(x0*QS));
    atomicAdd(c+2, __float2int_rn(x2*QS));
    atomicAdd(c+3, __float2int_rn(x0*x0*QS));
    atomicAdd(c+4, __float2int_rn(x2*x2*QS));
    atomicAdd(c+5, __float2int_rn(x0*x2*QS));
  }
  __syncthreads();
  for (int i = tid; i < AGG_N; i += 256) {
    long long s = (long long)accS[i] + accS[AGG_N+i] + accS[2*AGG_N+i] + accS[3*AGG_N+i];
    if (s) atomicAdd(&agg[i], (unsigned long long)s);
  }
}

// ------------- Kernel 2: finalize once -> scaled fp32 transposed tables -------------
__global__ void __launch_bounds__(256) mid_kernel(
    const unsigned long long* __restrict__ agg,
    float* ws,
    const float* __restrict__ bn_g, const float* __restrict__ bn_b,
    int B)
{
  __shared__ double aggd[AGG_N];               // 13.9 KB
  __shared__ float  Rl[4352];                  // 17.4 KB
  __shared__ double sh2p[256];                 // 2 KB
  __shared__ double margnE[NITV], margxE[NITV], margnB[NITV], margxB[NITV];
  __shared__ float  sArr[64], aE[64], aB[64];
  const int tid = threadIdx.x;

  for (int i = tid; i < 1088; i += 256)        // Rl <- raw tables (16B-aligned)
    ((uint4*)Rl)[i] = ((const uint4*)(ws + RAW_OFF))[i];
  for (int i = tid; i < AGG_N; i += 256) {
    long long v = (long long)agg[i];
    aggd[i] = (i % 6 == 0) ? (double)v : (double)v * QINV;
  }
  __syncthreads();

  // marginals
  if (tid < NITV) {
    double n = 0, sx = 0;
    for (int q = 0; q < NITV; ++q) {
      n  += aggd[(tid*NITV+q)*CELLF];
      sx += aggd[(tid*NITV+q)*CELLF + 1];
    }
    margnE[tid] = n; margxE[tid] = sx;
  } else if (tid >= 32 && tid < 32+NITV) {
    int q = tid - 32;
    double n = 0, sx = 0;
    for (int p = 0; p < NITV; ++p) {
      n  += aggd[(p*NITV+q)*CELLF];
      sx += aggd[(p*NITV+q)*CELLF + 2];
    }
    margnB[q] = n; margxB[q] = sx;
  }

  // E[h^2]*B, striped over p by 4 wave-groups
  {
    const int j = tid & 63, pg = tid >> 6;
    double sh2 = 0;
    for (int p = pg; p < NITV; p += 4) {
      const double Ue = (double)Rl[p*64+j];
      const double Ve = (double)Rl[1088 + p*64+j];
      for (int q = 0; q < NITV; ++q) {
        const double* c = &aggd[(p*NITV+q)*CELLF];
        double n = c[0], sx0 = c[1], sx2 = c[2], s00 = c[3], s22 = c[4], s02 = c[5];
        double Ub = (double)Rl[2176 + q*64+j];
        double Vb = (double)Rl[3264 + q*64+j];
        sh2 += s00*Ue*Ue + 2.0*sx0*Ue*Ve + n*Ve*Ve
             + s22*Ub*Ub + 2.0*sx2*Ub*Vb + n*Vb*Vb
             + 2.0*(s02*Ue*Ub + sx0*Ue*Vb + sx2*Ve*Ub + n*Ve*Vb);
      }
    }
    sh2p[tid] = sh2;
  }
  __syncthreads();

  if (tid < 64) {
    const int j = tid;
    double sh2 = (sh2p[j] + sh2p[64+j]) + (sh2p[128+j] + sh2p[192+j]);
    const double invB = 1.0 / (double)B;
    double mua = 0, mub = 0;
    for (int p = 0; p < NITV; ++p) {
      mua += margxE[p]*(double)Rl[p*64+j]      + margnE[p]*(double)Rl[1088+p*64+j];
      mub += margxB[p]*(double)Rl[2176+p*64+j] + margnB[p]*(double)Rl[3264+p*64+j];
    }
    mua *= invB; mub *= invB;
    double mu  = mua + mub;
    double var = sh2*invB - mu*mu;
    double s   = (double)bn_g[j] / sqrt(var + 1e-5);
    sArr[j] = (float)s;
    aE[j] = (float)(0.5*(double)bn_b[j] - s*mua);   // split shift between E and B parts
    aB[j] = (float)(0.5*(double)bn_b[j] - s*mub);
  }
  __syncthreads();

  // pack scaled tables, transposed [pair p][itv]: float4 {U_j0, U_j1, V_j0, V_j1}
  float4* EVT = (float4*)(ws + EVT_OFF);
  float4* BVT = (float4*)(ws + BVT_OFF);
  for (int idx = tid; idx < NITV*32; idx += 256) {
    int itv = idx >> 5, p = idx & 31;
    int j0 = 2*p, j1 = 2*p + 1;
    float sc0 = sArr[j0], sc1 = sArr[j1];
    float4 E;
    E.x = sc0 * Rl[itv*64+j0];
    E.y = sc1 * Rl[itv*64+j1];
    E.z = fmaf(sc0, Rl[1088+itv*64+j0], aE[j0]);
    E.w = fmaf(sc1, Rl[1088+itv*64+j1], aE[j1]);
    EVT[p*NITV + itv] = E;
    float4 Bv;
    Bv.x = sc0 * Rl[2176+itv*64+j0];
    Bv.y = sc1 * Rl[2176+itv*64+j1];
    Bv.z = fmaf(sc0, Rl[3264+itv*64+j0], aB[j0]);
    Bv.w = fmaf(sc1, Rl[3264+itv*64+j1], aB[j1]);
    BVT[p*NITV + itv] = Bv;
  }
}

// ------------- Kernel 3: apply (fp32, conflict-light b128 transposed reads) -------------
__global__ void __launch_bounds__(256) apply_kernel(
    const float* __restrict__ x, const float* __restrict__ ws,
    const float* __restrict__ f2_w, const float* __restrict__ f2_b,
    float* __restrict__ out, int B)
{
  __shared__ __align__(16) float4 tabs[2*544];   // EVT [0..544), BVT [544..1088)
  const int tid = threadIdx.x;

  // x loads issued early
  const int s0 = (blockIdx.x*256 + tid)*4;
  float xs0[4], xs2[4];
  int nv = 0;
  if (s0 + 4 <= B) {
    const float4* xp = (const float4*)(x + (size_t)s0*3);
    float4 a = xp[0], b = xp[1], c = xp[2];
    xs0[0]=a.x; xs2[0]=a.z;  xs0[1]=a.w; xs2[1]=b.y;
    xs0[2]=b.z; xs2[2]=c.x;  xs0[3]=c.y; xs2[3]=c.w;
    nv = 4;
  } else {
    for (int u = 0; u < 4; ++u) {
      int i = s0 + u;
      if (i < B) { xs0[nv] = x[3*(size_t)i]; xs2[nv] = x[3*(size_t)i+2]; ++nv; }
    }
  }

  for (int i = tid; i < 1088; i += 256)
    ((uint4*)tabs)[i] = ((const uint4*)(ws + EVT_OFF))[i];

  float te[16], tb[16];
  #pragma unroll
  for (int k = 0; k < 16; ++k) { te[k] = ws[THR_OFF+k]; tb[k] = ws[THR_OFF+16+k]; }
  const float b0 = f2_b[0], b1 = f2_b[1], b2 = f2_b[2];
  __syncthreads();

  float res[12];
  #pragma unroll
  for (int u = 0; u < 4; ++u) {
    if (u >= nv) break;
    float x0 = xs0[u], x2 = xs2[u];
    int iv0 = bsearch17(te, x0);
    int iv2 = bsearch17(tb, x2);
    const float4* ev = tabs + iv0;          // + p*17
    const float4* bv = tabs + 544 + iv2;
    float a0 = b0, a1 = b1, a2 = b2;
    #pragma unroll
    for (int p = 0; p < 32; ++p) {
      float4 e = ev[p*NITV];
      float4 v = bv[p*NITV];
      float h0 = fmaf(x0, e.x, e.z) + fmaf(x2, v.x, v.z);
      float h1 = fmaf(x0, e.y, e.w) + fmaf(x2, v.y, v.w);
      float r0 = fmaxf(h0, 0.f);
      float r1 = fmaxf(h1, 0.f);
      const int j = 2*p;
      a0 = fmaf(r0, f2_w[j],     fmaf(r1, f2_w[j+1],     a0));
      a1 = fmaf(r0, f2_w[64+j],  fmaf(r1, f2_w[64+j+1],  a1));
      a2 = fmaf(r0, f2_w[128+j], fmaf(r1, f2_w[128+j+1], a2));
    }
    res[u*3+0] = a0; res[u*3+1] = a1; res[u*3+2] = a2;
  }
  if (nv == 4) {
    float4* op = (float4*)(out + (size_t)s0*3);
    op[0] = make_float4(res[0], res[1], res[2],  res[3]);
    op[1] = make_float4(res[4], res[5], res[6],  res[7]);
    op[2] = make_float4(res[8], res[9], res[10], res[11]);
  } else {
    for (int u = 0; u < nv; ++u) {
      size_t i = (size_t)(s0 + u);
      out[3*i+0] = res[u*3+0]; out[3*i+1] = res[u*3+1]; out[3*i+2] = res[u*3+2];
    }
  }
}

extern "C" void kernel_launch(void* const* d_in, const int* in_sizes, int n_in,
                              void* d_out, int out_size, void* d_ws, size_t ws_size,
                              hipStream_t stream) {
  const float* x          = (const float*)d_in[0];
  const float* ehr_w      = (const float*)d_in[1];
  const float* ehr_b      = (const float*)d_in[2];
  const float* bio_w      = (const float*)d_in[5];
  const float* bio_b      = (const float*)d_in[6];
  const float* bio_qkv_w  = (const float*)d_in[7];
  const float* bio_qkv_b  = (const float*)d_in[8];
  const float* ehr_qkv_w  = (const float*)d_in[9];
  const float* ehr_qkv_b  = (const float*)d_in[10];
  const float* attn_in_w  = (const float*)d_in[13];
  const float* attn_in_b  = (const float*)d_in[14];
  const float* attn_out_w = (const float*)d_in[15];
  const float* attn_out_b = (const float*)d_in[16];
  const float* ab_proj_w  = (const float*)d_in[17];
  const float* ab_proj_b  = (const float*)d_in[18];
  const float* f1_w       = (const float*)d_in[19];
  const float* f1_b       = (const float*)d_in[20];
  const float* bn_g       = (const float*)d_in[21];
  const float* bn_b       = (const float*)d_in[22];
  const float* f2_w       = (const float*)d_in[23];
  const float* f2_b       = (const float*)d_in[24];
  float* out = (float*)d_out;
  float* ws  = (float*)d_ws;
  unsigned long long* agg = (unsigned long long*)d_ws;
  const int B = in_sizes[0] / 3;
  const int nblk = (B + 1023) / 1024;   // 4 samples/thread, 256 threads

  hipMemsetAsync(d_ws, 0, AGG_N*sizeof(unsigned long long), stream);
  hist_kernel<<<nblk+1, 256, 0, stream>>>(x, ehr_w, ehr_b, bio_w, bio_b,
      bio_qkv_w, bio_qkv_b, ehr_qkv_w, ehr_qkv_b,
      attn_in_w, attn_in_b, attn_out_w, attn_out_b,
      ab_proj_w, ab_proj_b, f1_w, f1_b, agg, ws, B, nblk);
  mid_kernel<<<1, 256, 0, stream>>>(agg, ws, bn_g, bn_b, B);
  apply_kernel<<<nblk, 256, 0, stream>>>(x, ws, f2_w, f2_b, out, B);
}